// Round 13
// baseline (602.440 us; speedup 1.0000x reference)
//
#include <hip/hip_runtime.h>

#define TTs 50
#define NUNITS 784   // 49 t x 16 tiles(64 rows)

using short8   = __attribute__((ext_vector_type(8))) short;
using ushort4v = __attribute__((ext_vector_type(4))) unsigned short;
using f32x4    = __attribute__((ext_vector_type(4))) float;
using int4v    = __attribute__((ext_vector_type(4))) int;

__device__ __forceinline__ unsigned short f2bf(float f) {
    unsigned u = __builtin_bit_cast(unsigned, f);
    u += 0x7FFFu + ((u >> 16) & 1u);          // RNE
    return (unsigned short)(u >> 16);
}
__device__ __forceinline__ float bf2f(unsigned short s) {
    unsigned u = ((unsigned)s) << 16;
    return __builtin_bit_cast(float, u);
}
__device__ __forceinline__ float frcp(float x) { return __builtin_amdgcn_rcpf(x); }
__device__ __forceinline__ float sigm(float x)  { return frcp(1.f + __expf(-x)); }
__device__ __forceinline__ float ftanh(float x) { return 1.f - 2.f * frcp(__expf(2.f * x) + 1.f); }

#define WQ_SCALE 512.f
#define EQ_SCALE 256.f
#define H_SCALE  127.f

// Counting sort (desc) + queue/flag init. perm[rank] = orig row.
// flags[u]=1 pre-marks DEAD units (t >= tilemax) as done.
__global__ __launch_bounds__(1024)
void sort_kernel(const int* __restrict__ lenq, const int* __restrict__ lenr,
                 int* __restrict__ perm, int* __restrict__ flags,
                 int* __restrict__ qhead, float* __restrict__ out)
{
    __shared__ int cnt[64];
    const int tid = threadIdx.x;
    if (tid == 0) out[0] = 0.f;
    if (tid == 1) __hip_atomic_store(qhead, 0, __ATOMIC_RELAXED, __HIP_MEMORY_SCOPE_AGENT);
    if (tid < 64) cnt[tid] = 0;
    __syncthreads();
    const int l = (tid < 512) ? lenq[tid] : lenr[tid - 512];   // 1..49
    atomicAdd(&cnt[l], 1);
    __syncthreads();
    if (tid == 0) {
        int acc = 0;
        for (int v = 49; v >= 1; --v) { int c = cnt[v]; cnt[v] = acc; acc += c; }
    }
    __syncthreads();
    const int rank = atomicAdd(&cnt[l], 1);
    perm[rank] = tid;
    __syncthreads();
    if (tid < NUNITS) {
        int t = tid >> 4, tile = tid & 15;
        int p0 = perm[tile * 64];
        int tmax = (p0 < 512) ? lenq[p0] : lenr[p0 - 512];
        __hip_atomic_store(&flags[tid], (t < tmax) ? 0 : 1,
                           __ATOMIC_RELAXED, __HIP_MEMORY_SCOPE_AGENT);
    }
}

// Pack W (f32 [512][1024]) -> int8 [col][k], scale 512.
// y=0: rows 0..255 -> Wxq ; y=1: rows 256..511 -> Whq
__global__ __launch_bounds__(256)
void pack_w_kernel(const float* __restrict__ W,
                   signed char* __restrict__ Wxq, signed char* __restrict__ Whq)
{
    __shared__ float ld[64][65];
    const int koff = blockIdx.y * 256;
    signed char* dst = blockIdx.y ? Whq : Wxq;
    const int k0 = (blockIdx.x & 3) * 64, c0 = (blockIdx.x >> 2) * 64;
    const int tid = threadIdx.x;
    #pragma unroll
    for (int i = 0; i < 16; ++i) {
        int idx = tid + i * 256;
        ld[idx >> 6][idx & 63] = W[(size_t)(koff + k0 + (idx >> 6)) * 1024 + c0 + (idx & 63)];
    }
    __syncthreads();
    #pragma unroll
    for (int j = 0; j < 2; ++j) {
        int idx = tid + j * 256;
        int cl = idx >> 3, kc = (idx & 7) * 8;
        unsigned long long u = 0;
        #pragma unroll
        for (int e = 0; e < 8; ++e) {
            float v = ld[kc + e][cl] * WQ_SCALE;
            int q = __float2int_rn(fminf(fmaxf(v, -127.f), 127.f));
            u |= (unsigned long long)(unsigned char)(signed char)q << (8 * e);
        }
        *(unsigned long long*)(dst + (size_t)(c0 + cl) * 256 + k0 + kc) = u;
    }
}

// Fused producer/consumer: 256 blocks x 1024 thr (16 waves).
// Consumer: lstm on 4 sorted rows (int8 MFMA, Whq in AGPRs, conflict-free LDS).
// Producer: X units (t, 64-row tile) popped from a global queue (t-ascending),
// computed with int8 MFMA (emb, Wx quantized), flag released agent-scope.
// Deadlock-free: a waiting block produces units itself (self-service).
__global__ __launch_bounds__(1024, 4)
void fused_kernel(unsigned short* __restrict__ X,
                  const signed char* __restrict__ Wxq,
                  const signed char* __restrict__ Whq,
                  const float* __restrict__ bias,
                  const float* __restrict__ p_i, const float* __restrict__ p_f,
                  const float* __restrict__ p_o,
                  const int* __restrict__ lenq, const int* __restrict__ lenr,
                  const int* __restrict__ perm,
                  const float* __restrict__ emb,
                  const int* __restrict__ idq, const int* __restrict__ idr,
                  int* __restrict__ flags, int* __restrict__ qhead,
                  unsigned short* __restrict__ hfin)
{
    __shared__ __align__(16) char hl[2 * 4 * 288];   // lstm h dbuf
    __shared__ __align__(16) char Aq[64 * 272];      // producer emb i8 staging
    __shared__ int Ls[64];
    __shared__ int Ids[64];
    __shared__ int bcs[2];

    const int tid = threadIdx.x;
    const int L = tid & 63, w = tid >> 6;
    const int blk = blockIdx.x;
    const int lanelo = L & 15, lhi = L >> 4;
    const int hh = w * 16 + lanelo;
    const int tile = blk >> 4;                 // 64-row tile for flags

    if (tid < 576) ((int*)hl)[tid] = 0;

    // ---- consumer setup ----
    int4v Bw[4][4];
    #pragma unroll
    for (int g = 0; g < 4; ++g)
        #pragma unroll
        for (int kc = 0; kc < 4; ++kc)
            Bw[g][kc] = *(const int4v*)(Whq + (size_t)(g * 256 + hh) * 256 + kc * 64 + lhi * 16);

    const unsigned short* xb = X + (size_t)(blk >> 2) * 16384;
    int xgoff[4];
    #pragma unroll
    for (int g = 0; g < 4; ++g)
        xgoff[g] = (g * 16 + w) * 256 + (blk & 3) * 64 + lanelo * 4 + lhi;

    const bool rdlane = (lanelo & 3) == 0;
    const int ard = (lanelo >> 2) * 288 + lhi * 16;
    const int awr = lhi * 288 + hh;

    const float pii = p_i[hh], pff = p_f[hh], poo = p_o[hh];
    const float INV = 1.f / (H_SCALE * WQ_SCALE);

    const int gr = perm[blk * 4 + lhi];
    const int len_ = (gr < 512) ? lenq[gr] : lenr[gr - 512];
    const int p0 = perm[blk * 4];
    const int blkmax = (p0 < 512) ? lenq[p0] : lenr[p0 - 512];

    // ---- producer setup (wave w owns cols w*64 .. w*64+63) ----
    const int cw = w * 64;
    float bcx[4];
    #pragma unroll
    for (int f = 0; f < 4; ++f) {
        int col = cw + f * 16 + lanelo;
        bcx[f] = bias[col] + ((col >= 512 && col < 768) ? 2.0f : 0.f);
    }
    const float INV2 = 1.f / (EQ_SCALE * WQ_SCALE);

    auto produce = [&](int u) {
        const int ut = u >> 4, utile = u & 15;
        if (tid < 64) {
            int p = perm[utile * 64 + tid];
            Ls[tid] = (p < 512) ? lenq[p] : lenr[p - 512];
            Ids[tid] = (p < 512) ? idq[p * TTs + ut] : idr[(p - 512) * TTs + ut];
        }
        __syncthreads();
        {
            int row = tid >> 4, seg = tid & 15;
            if (ut < Ls[row]) {
                const float* ep = emb + (size_t)Ids[row] * 256 + seg * 16;
                int4v pv;
                #pragma unroll
                for (int q = 0; q < 4; ++q) {
                    float4 e = *(const float4*)(ep + q * 4);
                    int b0 = __float2int_rn(fminf(fmaxf(e.x * EQ_SCALE, -127.f), 127.f)) & 255;
                    int b1 = __float2int_rn(fminf(fmaxf(e.y * EQ_SCALE, -127.f), 127.f)) & 255;
                    int b2 = __float2int_rn(fminf(fmaxf(e.z * EQ_SCALE, -127.f), 127.f)) & 255;
                    int b3 = __float2int_rn(fminf(fmaxf(e.w * EQ_SCALE, -127.f), 127.f)) & 255;
                    pv[q] = b0 | (b1 << 8) | (b2 << 16) | (b3 << 24);
                }
                *(int4v*)(Aq + row * 272 + seg * 16) = pv;
            }
        }
        __syncthreads();
        int4v Bx[4][4];
        #pragma unroll
        for (int f = 0; f < 4; ++f)
            #pragma unroll
            for (int kc = 0; kc < 4; ++kc)
                Bx[f][kc] = *(const int4v*)(Wxq + (size_t)(cw + f * 16 + lanelo) * 256 + kc * 64 + lhi * 16);
        #pragma unroll
        for (int rg = 0; rg < 4; ++rg) {
            int4v acc[4];
            #pragma unroll
            for (int f = 0; f < 4; ++f) acc[f] = (int4v){0, 0, 0, 0};
            #pragma unroll
            for (int kc = 0; kc < 4; ++kc) {
                int4v av = *(const int4v*)(Aq + (rg * 16 + lanelo) * 272 + kc * 64 + lhi * 16);
                #pragma unroll
                for (int f = 0; f < 4; ++f)
                    acc[f] = __builtin_amdgcn_mfma_i32_16x16x64_i8(av, Bx[f][kc], acc[f], 0, 0, 0);
            }
            size_t baseoff = (((size_t)(ut * 64 + utile * 4 + rg)) * 64) * 256 + (size_t)L * 4;
            #pragma unroll
            for (int f = 0; f < 4; ++f) {
                ushort4v v;
                #pragma unroll
                for (int j = 0; j < 4; ++j) v[j] = f2bf(fmaf((float)acc[f][j], INV2, bcx[f]));
                *(ushort4v*)(X + baseoff + (size_t)(w * 4 + f) * 256) = v;
            }
        }
        __syncthreads();     // all X stores complete (vmcnt drained) + Aq/Ls reuse guard
        if (tid == 0) {
            __threadfence();
            __hip_atomic_store(&flags[u], 1, __ATOMIC_RELEASE, __HIP_MEMORY_SCOPE_AGENT);
        }
    };

    auto pop_and_produce = [&]() -> bool {     // false => queue exhausted
        if (tid == 0) bcs[1] = atomicAdd(qhead, 1);
        __syncthreads();
        int u = bcs[1];
        __syncthreads();
        if (u >= NUNITS) return false;
        if (tid == 0) bcs[0] = __hip_atomic_load(&flags[u], __ATOMIC_RELAXED, __HIP_MEMORY_SCOPE_AGENT);
        __syncthreads();
        int dead = bcs[0];
        __syncthreads();
        if (!dead) produce(u);
        return true;
    };

    auto wait_flag = [&](int idx) {
        for (;;) {
            if (tid == 0) bcs[0] = __hip_atomic_load(&flags[idx], __ATOMIC_ACQUIRE, __HIP_MEMORY_SCOPE_AGENT);
            __syncthreads();
            int rdy = bcs[0];
            __syncthreads();
            if (rdy) return;
            if (!pop_and_produce()) __builtin_amdgcn_s_sleep(8);
        }
    };

    // ---- consumer main loop ----
    float cst = 0.f, hst = 0.f;
    int4v a[4];
    #pragma unroll
    for (int kc = 0; kc < 4; ++kc) a[kc] = (int4v){0, 0, 0, 0};

    wait_flag(tile);                           // X for t=0
    unsigned short xr[4], xn[4];
    #pragma unroll
    for (int g = 0; g < 4; ++g) xr[g] = xb[xgoff[g]];
    const unsigned short* xp = xb + 1048576;

    __syncthreads();

    for (int t = 0; t < blkmax; ++t) {
        const int rb = (t & 1) * 1152;
        const int wb = 1152 - rb;

        const bool more = (t + 1 < blkmax);
        if (more) wait_flag((t + 1) * 16 + tile);
        const unsigned short* xs = more ? xp : xb;
        #pragma unroll
        for (int g = 0; g < 4; ++g) xn[g] = xs[xgoff[g]];
        xp += 1048576;

        if (rdlane) {
            #pragma unroll
            for (int kc = 0; kc < 4; ++kc)
                a[kc] = *(const int4v*)(hl + rb + ard + kc * 64);
        }

        int4v acc[4];
        #pragma unroll
        for (int g = 0; g < 4; ++g) acc[g] = (int4v){0, 0, 0, 0};
        #pragma unroll
        for (int kc = 0; kc < 4; ++kc)
            #pragma unroll
            for (int g = 0; g < 4; ++g)
                acc[g] = __builtin_amdgcn_mfma_i32_16x16x64_i8(a[kc], Bw[g][kc], acc[g], 0, 0, 0);

        {
            float cv = cst;
            float zi = fmaf((float)acc[0][0], INV, bf2f(xr[0]));
            float zj = fmaf((float)acc[1][0], INV, bf2f(xr[1]));
            float zf = fmaf((float)acc[2][0], INV, bf2f(xr[2]));
            float zo = fmaf((float)acc[3][0], INV, bf2f(xr[3]));
            float iv = sigm(fmaf(pii, cv, zi));
            float fv = sigm(fmaf(pff, cv, zf));
            float jv = ftanh(zj);
            float cn = fv * cv + iv * jv;
            float ov = sigm(fmaf(poo, cn, zo));
            float hn = ov * ftanh(cn);
            bool upd = (t < len_);
            if (upd) { cst = cn; hst = hn; }
            hl[wb + awr] = (signed char)__float2int_rn(hst * H_SCALE);
        }
        __syncthreads();
        #pragma unroll
        for (int g = 0; g < 4; ++g) xr[g] = xn[g];
    }

    hfin[(size_t)gr * 256 + hh] = f2bf(hst);

    // ---- drain remaining producer units ----
    while (pop_and_produce()) {}
}

#define TS 64
#define KT 16
#define LDW (TS + 4)

// qM[512x256] = bf16 h(rows 0..511) @ fp32 M[256x256]
__global__ __launch_bounds__(256)
void gemm_qM_kernel(const unsigned short* __restrict__ hA, const float* __restrict__ B,
                    float* __restrict__ C)
{
    __shared__ float As[KT][LDW];
    __shared__ float Bs[KT][LDW];
    const int tid = threadIdx.x;
    const int tx = tid & 15, ty = tid >> 4;
    const int m0 = blockIdx.x * TS, n0 = blockIdx.y * TS;
    float acc[4][4] = {};
    for (int kk = 0; kk < 256; kk += KT) {
        #pragma unroll
        for (int i = 0; i < 4; ++i) {
            int l = tid + i * 256;
            As[l & 15][l >> 4] = bf2f(hA[(m0 + (l >> 4)) * 256 + kk + (l & 15)]);
            Bs[l >> 6][l & 63] = B[(kk + (l >> 6)) * 256 + n0 + (l & 63)];
        }
        __syncthreads();
        #pragma unroll
        for (int k = 0; k < KT; ++k) {
            float4 a4 = *(const float4*)&As[k][ty * 4];
            float4 b4 = *(const float4*)&Bs[k][tx * 4];
            float av[4] = {a4.x, a4.y, a4.z, a4.w};
            float bv[4] = {b4.x, b4.y, b4.z, b4.w};
            #pragma unroll
            for (int i = 0; i < 4; ++i)
                #pragma unroll
                for (int j = 0; j < 4; ++j)
                    acc[i][j] = fmaf(av[i], bv[j], acc[i][j]);
        }
        __syncthreads();
    }
    #pragma unroll
    for (int i = 0; i < 4; ++i) {
        float4 v = {acc[i][0], acc[i][1], acc[i][2], acc[i][3]};
        *(float4*)&C[(m0 + ty * 4 + i) * 256 + n0 + tx * 4] = v;
    }
}

// D[512x512] = fp32 qM[512x256] @ (bf16 r[512x256])^T
__global__ __launch_bounds__(256)
void gemm_D_kernel(const float* __restrict__ A, const unsigned short* __restrict__ hB,
                   float* __restrict__ C)
{
    __shared__ float As[KT][LDW];
    __shared__ float Bs[KT][LDW];
    const int tid = threadIdx.x;
    const int tx = tid & 15, ty = tid >> 4;
    const int m0 = blockIdx.x * TS, n0 = blockIdx.y * TS;
    float acc[4][4] = {};
    for (int kk = 0; kk < 256; kk += KT) {
        #pragma unroll
        for (int i = 0; i < 4; ++i) {
            int l = tid + i * 256;
            As[l & 15][l >> 4] = A[(m0 + (l >> 4)) * 256 + kk + (l & 15)];
            Bs[l & 15][l >> 4] = bf2f(hB[(n0 + (l >> 4)) * 256 + kk + (l & 15)]);
        }
        __syncthreads();
        #pragma unroll
        for (int k = 0; k < KT; ++k) {
            float4 a4 = *(const float4*)&As[k][ty * 4];
            float4 b4 = *(const float4*)&Bs[k][tx * 4];
            float av[4] = {a4.x, a4.y, a4.z, a4.w};
            float bv[4] = {b4.x, b4.y, b4.z, b4.w};
            #pragma unroll
            for (int i = 0; i < 4; ++i)
                #pragma unroll
                for (int j = 0; j < 4; ++j)
                    acc[i][j] = fmaf(av[i], bv[j], acc[i][j]);
        }
        __syncthreads();
    }
    #pragma unroll
    for (int i = 0; i < 4; ++i) {
        float4 v = {acc[i][0], acc[i][1], acc[i][2], acc[i][3]};
        *(float4*)&C[(m0 + ty * 4 + i) * 512 + n0 + tx * 4] = v;
    }
}

__global__ __launch_bounds__(256)
void loss_kernel(const float* __restrict__ D, const float* __restrict__ wd,
                 float* __restrict__ out)
{
    int idx = blockIdx.x * 256 + threadIdx.x;
    int j = idx & 511;
    float d   = D[idx];
    float pos = D[j * 512 + j];
    float ww  = wd[idx];
    float wp  = wd[j * 512 + j];
    float wn  = fmaxf(0.f, fmaf(ww, frcp(wp), -1.f));
    float v   = fmaxf(0.f, d - pos + wn);
    #pragma unroll
    for (int o = 32; o > 0; o >>= 1) v += __shfl_down(v, o);
    __shared__ float sm[4];
    if ((threadIdx.x & 63) == 0) sm[threadIdx.x >> 6] = v;
    __syncthreads();
    if (threadIdx.x == 0) atomicAdd(out, sm[0] + sm[1] + sm[2] + sm[3]);
}

extern "C" void kernel_launch(void* const* d_in, const int* in_sizes, int n_in,
                              void* d_out, int out_size, void* d_ws, size_t ws_size,
                              hipStream_t stream) {
    const int*   idq  = (const int*)d_in[0];
    const int*   idr  = (const int*)d_in[1];
    const int*   lenq = (const int*)d_in[2];
    const int*   lenr = (const int*)d_in[3];
    const float* wd   = (const float*)d_in[4];
    const float* emb  = (const float*)d_in[5];
    const float* W    = (const float*)d_in[6];
    const float* bias = (const float*)d_in[7];
    const float* p_i  = (const float*)d_in[8];
    const float* p_f  = (const float*)d_in[9];
    const float* p_o  = (const float*)d_in[10];
    const float* Mm   = (const float*)d_in[11];
    float* out = (float*)d_out;

    char* ws = (char*)d_ws;
    unsigned short* X    = (unsigned short*)ws;              // 49 MB-slices: 102,760,448 B
    char* p = ws + (size_t)49 * 1048576 * 2;
    unsigned short* hfin = (unsigned short*)p;  p += 1024 * 256 * 2;   // 512 KB
    signed char*    Wxq  = (signed char*)p;     p += 1024 * 256;       // 256 KB
    signed char*    Whq  = (signed char*)p;     p += 1024 * 256;       // 256 KB
    float* qM = (float*)p;  p += 512 * 256 * 4;                        // 512 KB
    float* D  = (float*)p;  p += 512 * 512 * 4;                        // 1 MB
    int* perm  = (int*)p;   p += 1024 * 4;
    int* flags = (int*)p;   p += NUNITS * 4;
    int* qhead = (int*)p;

    sort_kernel<<<1, 1024, 0, stream>>>(lenq, lenr, perm, flags, qhead, out);
    pack_w_kernel<<<dim3(64, 2), 256, 0, stream>>>(W, Wxq, Whq);
    fused_kernel<<<256, 1024, 0, stream>>>(X, Wxq, Whq, bias, p_i, p_f, p_o,
                                           lenq, lenr, perm, emb, idq, idr,
                                           flags, qhead, hfin);
    gemm_qM_kernel<<<dim3(8, 4), 256, 0, stream>>>(hfin, Mm, qM);
    gemm_D_kernel<<<dim3(8, 8), 256, 0, stream>>>(qM, hfin + 512 * 256, D);
    loss_kernel<<<1024, 256, 0, stream>>>(D, wd, out);
}